// Round 2
// baseline (226.146 us; speedup 1.0000x reference)
//
#include <hip/hip_runtime.h>
#include <math.h>
#include <stdint.h>

typedef _Float16 half8 __attribute__((ext_vector_type(8)));
typedef float floatx4 __attribute__((ext_vector_type(4)));

#define NTOK 16384
#define DIM  2048
#define NEXP 64
#define TPB  32                    // tokens per block
#define NBLK (NTOK / TPB)          // 512 blocks
#define KSPL 4                     // K-split across the 4 waves
#define KW   (DIM / KSPL)          // 512 k per wave
#define NST  (KW / 32)             // 16 MFMA k-steps per wave
#define RSTR 68                    // 64 + 4 pad -> 2-way bank aliasing only (free)
#define REDF (KSPL * TPB * RSTR)   // 8704 f32 = 34816 B LDS

// split fp32 -> f16 hi + scaled lo (2^11). hi+lo MFMA pair recovers ~fp32 accuracy.
__device__ __forceinline__ void split8(const float4& v0, const float4& v1,
                                       half8& hi, half8& lo) {
    const float av[8] = {v0.x, v0.y, v0.z, v0.w, v1.x, v1.y, v1.z, v1.w};
#pragma unroll
    for (int j = 0; j < 8; j++) {
        const _Float16 hh = (_Float16)av[j];
        hi[j] = hh;
        lo[j] = (_Float16)((av[j] - (float)hh) * 2048.0f);
    }
}

// Single kernel: no wprep, no workspace, no LDS staging of operands.
// Wave = K-split slice ks (512 k), 32 tokens (2 m-tiles), all 64 experts (4 tg).
// A frag: lane(col,quad) holds x[tok0 + m*16 + col][k0 + s*32 + quad*8 .. +8) (32 B contig).
// B frag: lane(col,quad) holds W[t*16 + col][k0 + s*32 + quad*8 .. +8).
// Register pipeline: A prefetch distance 2 (HBM), B distance 1 (L2-hot: W is 512 KB,
// resident in every XCD L2). Full unroll keeps all array indices compile-time (rule #20).
__global__ __launch_bounds__(256, 2)
void gating_kernel(const float* __restrict__ x, const float* __restrict__ W,
                   const float* __restrict__ bias, float* __restrict__ out)
{
    __shared__ float red[REDF];
    __shared__ float bsh[NEXP];

    const int tid  = threadIdx.x;
    const int lane = tid & 63;
    const int ks   = tid >> 6;          // 0..3 K-split index (wave id)
    const int col  = lane & 15;
    const int quad = lane >> 4;
    const int tok0 = blockIdx.x * TPB;
    const int k0   = ks * KW;

    if (tid < NEXP) bsh[tid] = bias[tid];

    const float* pA[2];
#pragma unroll
    for (int m = 0; m < 2; m++)
        pA[m] = x + (size_t)(tok0 + m * 16 + col) * DIM + k0 + quad * 8;
    const float* pB[4];
#pragma unroll
    for (int t = 0; t < 4; t++)
        pB[t] = W + (size_t)(t * 16 + col) * DIM + k0 + quad * 8;

    float4 Ab[3][2][2];   // [slot][m][half]
    float4 Bb[2][4][2];   // [slot][tg][half]
    floatx4 accm[2][4];
    floatx4 accl[2][4];
#pragma unroll
    for (int m = 0; m < 2; m++)
#pragma unroll
        for (int t = 0; t < 4; t++) { accm[m][t] = (floatx4){0,0,0,0}; accl[m][t] = (floatx4){0,0,0,0}; }

    // prologue: A steps 0,1 ; B step 0
#pragma unroll
    for (int s = 0; s < 2; s++)
#pragma unroll
        for (int m = 0; m < 2; m++)
#pragma unroll
            for (int h = 0; h < 2; h++)
                Ab[s][m][h] = *(const float4*)(pA[m] + s * 32 + h * 4);
#pragma unroll
    for (int t = 0; t < 4; t++)
#pragma unroll
        for (int h = 0; h < 2; h++)
            Bb[0][t][h] = *(const float4*)(pB[t] + h * 4);

#pragma unroll
    for (int s = 0; s < NST; s++) {
        if (s + 2 < NST) {
#pragma unroll
            for (int m = 0; m < 2; m++)
#pragma unroll
                for (int h = 0; h < 2; h++)
                    Ab[(s + 2) % 3][m][h] = *(const float4*)(pA[m] + (s + 2) * 32 + h * 4);
        }
        if (s + 1 < NST) {
#pragma unroll
            for (int t = 0; t < 4; t++)
#pragma unroll
                for (int h = 0; h < 2; h++)
                    Bb[(s + 1) & 1][t][h] = *(const float4*)(pB[t] + (s + 1) * 32 + h * 4);
        }
        half8 ah[2], al[2];
#pragma unroll
        for (int m = 0; m < 2; m++)
            split8(Ab[s % 3][m][0], Ab[s % 3][m][1], ah[m], al[m]);
#pragma unroll
        for (int t = 0; t < 4; t++) {
            half8 bh, bl;
            split8(Bb[s & 1][t][0], Bb[s & 1][t][1], bh, bl);
#pragma unroll
            for (int m = 0; m < 2; m++) {
                accm[m][t] = __builtin_amdgcn_mfma_f32_16x16x32_f16(ah[m], bh, accm[m][t], 0, 0, 0);
                accl[m][t] = __builtin_amdgcn_mfma_f32_16x16x32_f16(ah[m], bl, accl[m][t], 0, 0, 0);
                accl[m][t] = __builtin_amdgcn_mfma_f32_16x16x32_f16(al[m], bh, accl[m][t], 0, 0, 0);
            }
        }
    }

    // K-split partials: wave ks writes [32 tok][64 exp] slab.
    // C/D layout: row = quad*4 + r (token within m-tile), col = lane&15 (expert) [m89]
    const float inv = 1.0f / 2048.0f;
#pragma unroll
    for (int t = 0; t < 4; t++)
#pragma unroll
        for (int m = 0; m < 2; m++)
#pragma unroll
            for (int r = 0; r < 4; r++)
                red[(ks * TPB + m * 16 + quad * 4 + r) * RSTR + t * 16 + col] =
                    accm[m][t][r] + accl[m][t][r] * inv;
    __syncthreads();

    if (tid < TPB) {
        const int tk = tid;
        float v0 = -INFINITY, v1 = -INFINITY;
        int   i0 = 0, i1 = 0;
        for (int e = 0; e < NEXP; e++) {
            const float v = red[(0 * TPB + tk) * RSTR + e]
                          + red[(1 * TPB + tk) * RSTR + e]
                          + red[(2 * TPB + tk) * RSTR + e]
                          + red[(3 * TPB + tk) * RSTR + e] + bsh[e];
            if (v > v0)      { v1 = v0; i1 = i0; v0 = v; i0 = e; }
            else if (v > v1) { v1 = v; i1 = e; }
        }
        const float e1 = expf(v1 - v0);   // v1 <= v0: stable
        const float sden = 1.f + e1;
        const int   g  = tok0 + tk;
        out[2 * g + 0] = 1.f / sden;
        out[2 * g + 1] = e1 / sden;
        out[2 * NTOK + 2 * g + 0] = (float)i0;
        out[2 * NTOK + 2 * g + 1] = (float)i1;
    }
}

extern "C" void kernel_launch(void* const* d_in, const int* in_sizes, int n_in,
                              void* d_out, int out_size, void* d_ws, size_t ws_size,
                              hipStream_t stream) {
    (void)d_ws; (void)ws_size;
    const float* x    = (const float*)d_in[0];
    const float* W    = (const float*)d_in[1];
    const float* bias = (const float*)d_in[2];
    float*       out  = (float*)d_out;
    hipLaunchKernelGGL(gating_kernel, dim3(NBLK), dim3(256), 0, stream,
                       x, W, bias, out);
}